// Round 1
// baseline (133.275 us; speedup 1.0000x reference)
//
#include <hip/hip_runtime.h>
#include <stdint.h>

// BitNetLinear eval forward on MI355X (gfx950).
// M = B*S = 32768, K = 1024 (in_features), N = 1024 (out_features).
//
// Pipeline:
//   k1: absmax(x)        -> ws.xmax_bits (atomicMax on float bits; exact, deterministic)
//   k2: sum|W| partials  -> ws.partials[256] (double, fixed order; deterministic)
//   k3: finalize         -> w_scale = sum/2^20, i_scale = xmax/127
//   k4: quantize W -> ternary int8 qw [N][K]
//   k5: quantize x -> int8 qx [M][K]
//   k6: int8 MFMA GEMM (128x128 tile, BK=128, global_load_lds + XOR swizzle)
//       epilogue: (float)acc * w_scale * i_scale + bias  (matches ref op order)

#define MK_M 32768
#define MK_K 1024
#define MK_N 1024

typedef __attribute__((ext_vector_type(4))) int int32x4;

// ---- workspace layout ----
// [0]      unsigned xmax_bits
// [4]      float w_scale
// [8]      float i_scale
// [16]     double partials[256]
// [4096]   qw  (N*K int8 = 1 MB)
// [4096+1M] qx (M*K int8 = 32 MB)
#define WS_QW_OFF 4096
#define WS_QX_OFF (4096 + (1 << 20))
#define WS_NEEDED (WS_QX_OFF + (size_t)MK_M * MK_K)

__global__ void kmax_x(const float4* __restrict__ x4, unsigned* __restrict__ xmax, long n4) {
    float m = 0.f;
    long stride = (long)gridDim.x * blockDim.x;
    for (long i = (long)blockIdx.x * blockDim.x + threadIdx.x; i < n4; i += stride) {
        float4 v = x4[i];
        m = fmaxf(m, fmaxf(fmaxf(fabsf(v.x), fabsf(v.y)), fmaxf(fabsf(v.z), fabsf(v.w))));
    }
    #pragma unroll
    for (int off = 1; off < 64; off <<= 1) m = fmaxf(m, __shfl_xor(m, off));
    __shared__ float sm[4];
    int lane = threadIdx.x & 63, wid = threadIdx.x >> 6;
    if (lane == 0) sm[wid] = m;
    __syncthreads();
    if (threadIdx.x == 0) {
        float b = fmaxf(fmaxf(sm[0], sm[1]), fmaxf(sm[2], sm[3]));
        atomicMax(xmax, __float_as_uint(b));  // all values >= 0: uint order == float order
    }
}

__global__ void ksum_w(const float4* __restrict__ w4, double* __restrict__ partials) {
    // n = 2^20 floats = 2^18 float4. 256 blocks x 256 threads, 4 iters each.
    double s = 0.0;
    for (int i = blockIdx.x * 256 + threadIdx.x; i < (1 << 18); i += 256 * 256) {
        float4 v = w4[i];
        s += (double)fabsf(v.x);
        s += (double)fabsf(v.y);
        s += (double)fabsf(v.z);
        s += (double)fabsf(v.w);
    }
    __shared__ double sd[256];
    sd[threadIdx.x] = s;
    __syncthreads();
    for (int h = 128; h > 0; h >>= 1) {
        if ((int)threadIdx.x < h) sd[threadIdx.x] += sd[threadIdx.x + h];
        __syncthreads();
    }
    if (threadIdx.x == 0) partials[blockIdx.x] = sd[0];
}

__global__ void kfin(const double* __restrict__ partials, const unsigned* __restrict__ xmax,
                     float* __restrict__ wscp, float* __restrict__ iscp) {
    if (threadIdx.x == 0 && blockIdx.x == 0) {
        double s = 0.0;
        for (int i = 0; i < 256; ++i) s += partials[i];
        *wscp = (float)(s / 1048576.0);               // mean|W| (2^20 elements)
        *iscp = __uint_as_float(*xmax) / 127.0f;      // fp32 divide, matches ref
    }
}

__global__ void kquant_w(const float4* __restrict__ w4, unsigned* __restrict__ qw,
                         const float* __restrict__ wscp) {
    float thr = 0.5f * (*wscp);
    int stride = gridDim.x * blockDim.x;
    for (int i = blockIdx.x * blockDim.x + threadIdx.x; i < (1 << 18); i += stride) {
        float4 v = w4[i];
        int q0 = (fabsf(v.x) > thr) ? (v.x > 0.f ? 1 : -1) : 0;
        int q1 = (fabsf(v.y) > thr) ? (v.y > 0.f ? 1 : -1) : 0;
        int q2 = (fabsf(v.z) > thr) ? (v.z > 0.f ? 1 : -1) : 0;
        int q3 = (fabsf(v.w) > thr) ? (v.w > 0.f ? 1 : -1) : 0;
        qw[i] = (q0 & 0xff) | ((q1 & 0xff) << 8) | ((q2 & 0xff) << 16) | ((q3 & 0xff) << 24);
    }
}

__global__ void kquant_x(const float4* __restrict__ x4, unsigned* __restrict__ qx,
                         const float* __restrict__ iscp, long n4) {
    float isc = *iscp;
    long stride = (long)gridDim.x * blockDim.x;
    for (long i = (long)blockIdx.x * blockDim.x + threadIdx.x; i < n4; i += stride) {
        float4 v = x4[i];
        // must be IEEE divide + rint (half-to-even) to match jnp.round(x / i_scale)
        float q0 = fminf(fmaxf(rintf(v.x / isc), -128.f), 127.f);
        float q1 = fminf(fmaxf(rintf(v.y / isc), -128.f), 127.f);
        float q2 = fminf(fmaxf(rintf(v.z / isc), -128.f), 127.f);
        float q3 = fminf(fmaxf(rintf(v.w / isc), -128.f), 127.f);
        int i0 = (int)q0, i1 = (int)q1, i2 = (int)q2, i3 = (int)q3;
        qx[i] = (i0 & 0xff) | ((i1 & 0xff) << 8) | ((i2 & 0xff) << 16) | ((i3 & 0xff) << 24);
    }
}

// ---- int8 GEMM: out[m][n] = sum_k qx[m][k] * qw[n][k]  (B^T layout) ----
// 128x128 tile, BK=128 (rows are 128B in LDS), 4 waves in 2x2 arrangement,
// each wave computes 64x64 via 4x4 frags of mfma_i32_16x16x64_i8.
// LDS layout is chunk-swizzled: lds[row][ch] = global[row][ch ^ (row&7)]
// (16B chunks). Achieved by pre-swizzling the GLOBAL source address of
// global_load_lds (LDS dest stays linear: base + lane*16). Readers XOR the
// chunk index by (row&7) -> ds_read_b128 lands on 8 distinct bank groups
// per 8 rows => 2-way (free) instead of 16-way conflict.
__global__ __launch_bounds__(256) void kgemm(
    const char* __restrict__ qx, const char* __restrict__ qw,
    const float* __restrict__ bias, const float* __restrict__ wscp,
    const float* __restrict__ iscp, float* __restrict__ out)
{
    __shared__ __align__(16) char As[128 * 128];
    __shared__ __align__(16) char Bs[128 * 128];

    const int t = threadIdx.x;
    const int l = t & 63, w = t >> 6;
    const int wm = w >> 1, wn = w & 1;

    // XCD-bijective swizzle: 2048 blocks, 8 XCDs, 256 per XCD (contiguous M-range per XCD)
    const int bid = blockIdx.x;
    const int wg = (bid & 7) * 256 + (bid >> 3);
    const int tm = wg >> 3, tn = wg & 7;
    const long m0 = (long)tm * 128;
    const int n0 = tn * 128;

    int32x4 acc[4][4];
    #pragma unroll
    for (int mi = 0; mi < 4; ++mi)
        #pragma unroll
        for (int ni = 0; ni < 4; ++ni) acc[mi][ni] = (int32x4)0;

    // staging addresses: iteration i stages rows [i*32 + w*8 + (l>>3)]
    const int srow = l >> 3;
    const int gch = (l & 7) ^ srow;  // pre-swizzled global chunk
    const char* gA = qx + (m0 + w * 8 + srow) * MK_K + gch * 16;
    const char* gB = qw + ((long)n0 + w * 8 + srow) * MK_K + gch * 16;
    char* lA = As + t * 16;
    char* lB = Bs + t * 16;

    for (int kt = 0; kt < 8; ++kt) {
        const char* ga = gA + kt * 128;
        const char* gb = gB + kt * 128;
        #pragma unroll
        for (int i = 0; i < 4; ++i) {
            __builtin_amdgcn_global_load_lds(
                (const __attribute__((address_space(1))) void*)(ga + (long)i * 32 * MK_K),
                (__attribute__((address_space(3))) void*)(lA + i * 4096), 16, 0, 0);
            __builtin_amdgcn_global_load_lds(
                (const __attribute__((address_space(1))) void*)(gb + (long)i * 32 * MK_K),
                (__attribute__((address_space(3))) void*)(lB + i * 4096), 16, 0, 0);
        }
        __syncthreads();  // drains vmcnt before any wave reads LDS

        #pragma unroll
        for (int kk = 0; kk < 2; ++kk) {
            int32x4 af[4], bf[4];
            #pragma unroll
            for (int mi = 0; mi < 4; ++mi) {
                int row = wm * 64 + mi * 16 + (l & 15);
                int ch = (kk * 4 + (l >> 4)) ^ (row & 7);
                af[mi] = *(const int32x4*)(As + row * 128 + ch * 16);
            }
            #pragma unroll
            for (int ni = 0; ni < 4; ++ni) {
                int row = wn * 64 + ni * 16 + (l & 15);
                int ch = (kk * 4 + (l >> 4)) ^ (row & 7);
                bf[ni] = *(const int32x4*)(Bs + row * 128 + ch * 16);
            }
            #pragma unroll
            for (int mi = 0; mi < 4; ++mi)
                #pragma unroll
                for (int ni = 0; ni < 4; ++ni)
                    acc[mi][ni] = __builtin_amdgcn_mfma_i32_16x16x64_i8(af[mi], bf[ni], acc[mi][ni], 0, 0, 0);
        }
        __syncthreads();  // all waves done reading before next stage overwrites
    }

    // epilogue: C/D layout col = lane&15, row = (lane>>4)*4 + reg
    const float wsc = *wscp, isc = *iscp;
    const int crow = (l >> 4) * 4;
    const int ccol = l & 15;
    #pragma unroll
    for (int mi = 0; mi < 4; ++mi) {
        #pragma unroll
        for (int ni = 0; ni < 4; ++ni) {
            long r0 = m0 + wm * 64 + mi * 16 + crow;
            int c = n0 + wn * 64 + ni * 16 + ccol;
            float b = bias[c];
            #pragma unroll
            for (int j = 0; j < 4; ++j) {
                float v = ((float)acc[mi][ni][j] * wsc) * isc + b;
                out[(r0 + j) * MK_N + c] = v;
            }
        }
    }
}

extern "C" void kernel_launch(void* const* d_in, const int* in_sizes, int n_in,
                              void* d_out, int out_size, void* d_ws, size_t ws_size,
                              hipStream_t stream) {
    const float* x = (const float*)d_in[0];
    const float* wt = (const float*)d_in[1];
    const float* bias = (const float*)d_in[2];
    float* out = (float*)d_out;

    if (ws_size < WS_NEEDED) return;  // workspace too small (should not happen)

    char* ws = (char*)d_ws;
    unsigned* xmax = (unsigned*)ws;
    float* wscp = (float*)(ws + 4);
    float* iscp = (float*)(ws + 8);
    double* partials = (double*)(ws + 16);
    char* qw = ws + WS_QW_OFF;
    char* qx = ws + WS_QX_OFF;

    const long n_x = (long)in_sizes[0];   // 33554432
    const long n4_x = n_x >> 2;

    hipMemsetAsync(d_ws, 0, 16, stream);  // zero xmax_bits (capture-safe)

    kmax_x<<<2048, 256, 0, stream>>>((const float4*)x, xmax, n4_x);
    ksum_w<<<256, 256, 0, stream>>>((const float4*)wt, partials);
    kfin<<<1, 64, 0, stream>>>(partials, xmax, wscp, iscp);
    kquant_w<<<256, 256, 0, stream>>>((const float4*)wt, (unsigned*)qw, wscp);
    kquant_x<<<2048, 256, 0, stream>>>((const float4*)x, (unsigned*)qx, iscp, n4_x);

    const int grid = (MK_M / 128) * (MK_N / 128);  // 2048
    kgemm<<<grid, 256, 0, stream>>>(qx, qw, bias, wscp, iscp, out);
}